// Round 1
// baseline (2985.641 us; speedup 1.0000x reference)
//
#include <hip/hip_runtime.h>

#define NODES 50000
#define EDGES 800000
#define DIM 128
#define EPS_BN 1e-5f

// ---------------- degree ----------------
__global__ __launch_bounds__(256) void degree_kernel(const int* __restrict__ src,
                                                     const int* __restrict__ dst,
                                                     float* __restrict__ deg_out,
                                                     float* __restrict__ deg_in) {
    int e = blockIdx.x * 256 + threadIdx.x;
    if (e < EDGES) {
        atomicAdd(&deg_out[src[e]], 1.0f);
        atomicAdd(&deg_in[dst[e]], 1.0f);
    }
}

__global__ __launch_bounds__(256) void degnorm_kernel(float* __restrict__ deg, int n) {
    int i = blockIdx.x * 256 + threadIdx.x;
    if (i < n) deg[i] = rsqrtf(fmaxf(deg[i], 1.0f));
}

// ---------------- SpMM aggregate (push, atomics) ----------------
// agg[dst] += h[src] * dnorm_out[src];  one thread per (edge, 4 features)
__global__ __launch_bounds__(256) void scatter_kernel(const float* __restrict__ h,
                                                      const int* __restrict__ src,
                                                      const int* __restrict__ dst,
                                                      const float* __restrict__ dnorm,
                                                      float* __restrict__ agg) {
    long idx = (long)blockIdx.x * 256 + threadIdx.x;   // E*32 threads
    int e = (int)(idx >> 5);
    if (e >= EDGES) return;
    int f = ((int)idx & 31) * 4;
    int s = src[e], d = dst[e];
    float sc = dnorm[s];
    const float4 v = *(const float4*)(h + (size_t)s * DIM + f);
    float* p = agg + (size_t)d * DIM + f;
    atomicAdd(p + 0, v.x * sc);
    atomicAdd(p + 1, v.y * sc);
    atomicAdd(p + 2, v.z * sc);
    atomicAdd(p + 3, v.w * sc);
}

// ---------------- GEMM: out[i][:] = dnorm_in[i] * (agg[i][:] @ W) + bias ----------------
// 32 rows x 128 cols per block; 256 threads; 4x4 register tile per thread.
__global__ __launch_bounds__(256) void gemm_kernel(const float* __restrict__ A,
                                                   const float* __restrict__ dnorm,
                                                   const float* __restrict__ W,
                                                   const float* __restrict__ bias,
                                                   float* __restrict__ out) {
    __shared__ float Ws[DIM * DIM];   // 64 KB, W[k][j]
    __shared__ float As[DIM * 32];    // 16 KB, A^T: As[k*32 + r]

    int t = threadIdx.x;
    int row0 = blockIdx.x * 32;

    // stage W
    for (int i = t * 4; i < DIM * DIM; i += 256 * 4)
        *(float4*)&Ws[i] = *(const float4*)&W[i];

    // stage A tile transposed: thread t -> row r = t>>3, k-chunk (t&7)*16
    {
        int r = t >> 3;
        int k0 = (t & 7) * 16;
        int grow = row0 + r;
        if (grow < NODES) {
            const float* ap = A + (size_t)grow * DIM + k0;
            #pragma unroll
            for (int i = 0; i < 4; ++i) {
                float4 v = *(const float4*)(ap + i * 4);
                As[(k0 + i * 4 + 0) * 32 + r] = v.x;
                As[(k0 + i * 4 + 1) * 32 + r] = v.y;
                As[(k0 + i * 4 + 2) * 32 + r] = v.z;
                As[(k0 + i * 4 + 3) * 32 + r] = v.w;
            }
        }
    }
    __syncthreads();

    int cg = t & 31;   // col group: cols cg*4 .. cg*4+3
    int rg = t >> 5;   // row group: rows rg*4 .. rg*4+3
    float acc[4][4];
    #pragma unroll
    for (int i = 0; i < 4; ++i)
        #pragma unroll
        for (int j = 0; j < 4; ++j) acc[i][j] = 0.f;

    #pragma unroll 4
    for (int k = 0; k < DIM; ++k) {
        float4 av = *(float4*)&As[k * 32 + rg * 4];
        float4 wv = *(float4*)&Ws[k * DIM + cg * 4];
        acc[0][0] += av.x * wv.x; acc[0][1] += av.x * wv.y; acc[0][2] += av.x * wv.z; acc[0][3] += av.x * wv.w;
        acc[1][0] += av.y * wv.x; acc[1][1] += av.y * wv.y; acc[1][2] += av.y * wv.z; acc[1][3] += av.y * wv.w;
        acc[2][0] += av.z * wv.x; acc[2][1] += av.z * wv.y; acc[2][2] += av.z * wv.z; acc[2][3] += av.z * wv.w;
        acc[3][0] += av.w * wv.x; acc[3][1] += av.w * wv.y; acc[3][2] += av.w * wv.z; acc[3][3] += av.w * wv.w;
    }

    float4 bv = *(const float4*)&bias[cg * 4];
    #pragma unroll
    for (int ri = 0; ri < 4; ++ri) {
        int row = row0 + rg * 4 + ri;
        if (row < NODES) {
            float sc = dnorm[row];
            float4 o;
            o.x = sc * acc[ri][0] + bv.x;
            o.y = sc * acc[ri][1] + bv.y;
            o.z = sc * acc[ri][2] + bv.z;
            o.w = sc * acc[ri][3] + bv.w;
            *(float4*)&out[(size_t)row * DIM + cg * 4] = o;
        }
    }
}

// ---------------- BN column stats (sum, sumsq) ----------------
__global__ __launch_bounds__(256) void bn_stats_kernel(const float* __restrict__ h,
                                                       float* __restrict__ stats) {
    __shared__ float ssum[DIM], ssq[DIM];
    int t = threadIdx.x;
    if (t < DIM) { ssum[t] = 0.f; ssq[t] = 0.f; }
    __syncthreads();
    int c = t & 127;
    int rstep = gridDim.x * 2;
    float lsum = 0.f, lsq = 0.f;
    for (int r = blockIdx.x * 2 + (t >> 7); r < NODES; r += rstep) {
        float v = h[(size_t)r * DIM + c];
        lsum += v;
        lsq += v * v;
    }
    atomicAdd(&ssum[c], lsum);
    atomicAdd(&ssq[c], lsq);
    __syncthreads();
    if (t < DIM) {
        atomicAdd(&stats[t], ssum[t]);
        atomicAdd(&stats[DIM + t], ssq[t]);
    }
}

// ---------------- BN apply + ReLU (in place) ----------------
__global__ __launch_bounds__(256) void bn_relu_kernel(float* __restrict__ h,
                                                      const float* __restrict__ stats,
                                                      const float* __restrict__ g,
                                                      const float* __restrict__ be) {
    size_t idx = (size_t)blockIdx.x * 256 + threadIdx.x;  // over N*32 float4s
    if (idx >= (size_t)NODES * 32) return;
    int c = (int)(idx & 31) * 4;
    const float invN = 1.0f / NODES;
    float4 v = *(float4*)(h + idx * 4);
    float vv[4] = {v.x, v.y, v.z, v.w};
    float o[4];
    #pragma unroll
    for (int j = 0; j < 4; ++j) {
        float mu = stats[c + j] * invN;
        float var = stats[DIM + c + j] * invN - mu * mu;
        float w = g[c + j] * rsqrtf(var + EPS_BN);
        o[j] = fmaxf(w * (vv[j] - mu) + be[c + j], 0.f);
    }
    float4 r = {o[0], o[1], o[2], o[3]};
    *(float4*)(h + idx * 4) = r;
}

// ---------------- BN apply + residual + ReLU (in place on out) ----------------
__global__ __launch_bounds__(256) void bn_res_relu_kernel(float* __restrict__ out,
                                                          const float* __restrict__ h1,
                                                          const float* __restrict__ stats,
                                                          const float* __restrict__ g,
                                                          const float* __restrict__ be) {
    size_t idx = (size_t)blockIdx.x * 256 + threadIdx.x;
    if (idx >= (size_t)NODES * 32) return;
    int c = (int)(idx & 31) * 4;
    const float invN = 1.0f / NODES;
    float4 v = *(float4*)(out + idx * 4);
    float4 r1 = *(const float4*)(h1 + idx * 4);
    float vv[4] = {v.x, v.y, v.z, v.w};
    float rr[4] = {r1.x, r1.y, r1.z, r1.w};
    float o[4];
    #pragma unroll
    for (int j = 0; j < 4; ++j) {
        float mu = stats[c + j] * invN;
        float var = stats[DIM + c + j] * invN - mu * mu;
        float w = g[c + j] * rsqrtf(var + EPS_BN);
        o[j] = fmaxf(w * (vv[j] - mu) + be[c + j] + rr[j], 0.f);
    }
    float4 r = {o[0], o[1], o[2], o[3]};
    *(float4*)(out + idx * 4) = r;
}

extern "C" void kernel_launch(void* const* d_in, const int* in_sizes, int n_in,
                              void* d_out, int out_size, void* d_ws, size_t ws_size,
                              hipStream_t stream) {
    const float* x      = (const float*)d_in[0];
    const int*   src    = (const int*)d_in[1];
    const int*   dst    = (const int*)d_in[2];
    const float* W1     = (const float*)d_in[3];
    const float* b1     = (const float*)d_in[4];
    const float* gamma1 = (const float*)d_in[5];
    const float* beta1  = (const float*)d_in[6];
    const float* W2     = (const float*)d_in[7];
    const float* b2     = (const float*)d_in[8];
    const float* gamma2 = (const float*)d_in[9];
    const float* beta2  = (const float*)d_in[10];
    float* out = (float*)d_out;

    // workspace layout (floats):
    //   deg_out[N] | deg_in[N] | stats[256] | agg[N*128] | h1[N*128]
    float* ws       = (float*)d_ws;
    float* deg_out  = ws;
    float* deg_in   = ws + NODES;
    float* stats    = ws + 2 * NODES;
    float* agg      = stats + 2 * DIM;
    float* h1       = agg + (size_t)NODES * DIM;

    const int THREADS = 256;
    const int grid_deg   = (EDGES + THREADS - 1) / THREADS;
    const int grid_dn    = (2 * NODES + THREADS - 1) / THREADS;
    const int grid_scat  = (int)(((long)EDGES * 32 + THREADS - 1) / THREADS);
    const int grid_gemm  = (NODES + 31) / 32;
    const int grid_stats = 1024;
    const int grid_elem  = (NODES * 32 + THREADS - 1) / THREADS;

    // zero: deg_out, deg_in, stats, agg (contiguous)
    hipMemsetAsync(d_ws, 0, (size_t)(2 * NODES + 2 * DIM + (size_t)NODES * DIM) * 4, stream);

    // degrees
    degree_kernel<<<grid_deg, THREADS, 0, stream>>>(src, dst, deg_out, deg_in);
    degnorm_kernel<<<grid_dn, THREADS, 0, stream>>>(deg_out, 2 * NODES);

    // layer 1
    scatter_kernel<<<grid_scat, THREADS, 0, stream>>>(x, src, dst, deg_out, agg);
    gemm_kernel<<<grid_gemm, THREADS, 0, stream>>>(agg, deg_in, W1, b1, h1);
    bn_stats_kernel<<<grid_stats, THREADS, 0, stream>>>(h1, stats);
    bn_relu_kernel<<<grid_elem, THREADS, 0, stream>>>(h1, stats, gamma1, beta1);

    // re-zero stats + agg (contiguous)
    hipMemsetAsync(stats, 0, (size_t)(2 * DIM + (size_t)NODES * DIM) * 4, stream);

    // layer 2
    scatter_kernel<<<grid_scat, THREADS, 0, stream>>>(h1, src, dst, deg_out, agg);
    gemm_kernel<<<grid_gemm, THREADS, 0, stream>>>(agg, deg_in, W2, b2, out);
    bn_stats_kernel<<<grid_stats, THREADS, 0, stream>>>(out, stats);
    bn_res_relu_kernel<<<grid_elem, THREADS, 0, stream>>>(out, h1, stats, gamma2, beta2);
}

// Round 2
// 636.189 us; speedup vs baseline: 4.6930x; 4.6930x over previous
//
#include <hip/hip_runtime.h>

#define NODES 50000
#define EDGES 800000
#define DIM 128
#define EPS_BN 1e-5f
#define SCAN_T 1024
#define SCAN_CH ((NODES + SCAN_T - 1) / SCAN_T)   // 49

// ---------------- degree histogram (int) ----------------
__global__ __launch_bounds__(256) void degree_int_kernel(const int* __restrict__ src,
                                                         const int* __restrict__ dst,
                                                         int* __restrict__ cnt_out,
                                                         int* __restrict__ cnt_in) {
    int e = blockIdx.x * 256 + threadIdx.x;
    if (e < EDGES) {
        atomicAdd(&cnt_out[src[e]], 1);
        atomicAdd(&cnt_in[dst[e]], 1);
    }
}

// ---------------- single-block exclusive scan of cnt_in -> row_ptr ----------------
__global__ __launch_bounds__(SCAN_T) void scan_kernel(const int* __restrict__ cnt,
                                                      int* __restrict__ row_ptr) {
    __shared__ int part[SCAN_T];
    int tid = threadIdx.x;
    int base = tid * SCAN_CH;
    int sum = 0;
    for (int i = 0; i < SCAN_CH; ++i) {
        int idx = base + i;
        if (idx < NODES) sum += cnt[idx];
    }
    part[tid] = sum;
    __syncthreads();
    for (int off = 1; off < SCAN_T; off <<= 1) {
        int v = (tid >= off) ? part[tid - off] : 0;
        __syncthreads();
        part[tid] += v;
        __syncthreads();
    }
    int run = part[tid] - sum;   // exclusive prefix
    for (int i = 0; i < SCAN_CH; ++i) {
        int idx = base + i;
        if (idx < NODES) {
            row_ptr[idx] = run;
            run += cnt[idx];
        }
    }
    if (tid == SCAN_T - 1) row_ptr[NODES] = part[SCAN_T - 1];
}

// ---------------- degree -> rsqrt norm (float) ----------------
__global__ __launch_bounds__(256) void degnorm_kernel(const int* __restrict__ cnt_out,
                                                      const int* __restrict__ cnt_in,
                                                      float* __restrict__ dn_out,
                                                      float* __restrict__ dn_in) {
    int i = blockIdx.x * 256 + threadIdx.x;
    if (i < NODES) {
        dn_out[i] = rsqrtf((float)max(cnt_out[i], 1));
        dn_in[i]  = rsqrtf((float)max(cnt_in[i], 1));
    }
}

// ---------------- CSR fill (counting sort by dst) ----------------
__global__ __launch_bounds__(256) void csr_fill_kernel(const int* __restrict__ src,
                                                       const int* __restrict__ dst,
                                                       const int* __restrict__ row_ptr,
                                                       int* __restrict__ cursor,
                                                       int* __restrict__ csr_src) {
    int e = blockIdx.x * 256 + threadIdx.x;
    if (e < EDGES) {
        int d = dst[e];
        int pos = row_ptr[d] + atomicAdd(&cursor[d], 1);
        csr_src[pos] = src[e];
    }
}

// ---------------- pull aggregation: agg[n] = dn_in[n] * sum_{s in N(n)} dn_out[s]*h[s] ----
// one wave (64 lanes) per dst node; lane l holds features 2l, 2l+1
__global__ __launch_bounds__(256) void pull_kernel(const float* __restrict__ h,
                                                   const int* __restrict__ row_ptr,
                                                   const int* __restrict__ csr_src,
                                                   const float* __restrict__ dn_out,
                                                   const float* __restrict__ dn_in,
                                                   float* __restrict__ agg) {
    int wid = threadIdx.x >> 6;
    int node = blockIdx.x * 4 + wid;
    if (node >= NODES) return;
    int lane2 = (threadIdx.x & 63) * 2;
    int beg = row_ptr[node];
    int end = row_ptr[node + 1];
    float ax = 0.f, ay = 0.f;
    int e = beg;
    for (; e + 1 < end; e += 2) {
        int s0 = csr_src[e];
        int s1 = csr_src[e + 1];
        float sc0 = dn_out[s0];
        float sc1 = dn_out[s1];
        float2 v0 = *(const float2*)(h + (size_t)s0 * DIM + lane2);
        float2 v1 = *(const float2*)(h + (size_t)s1 * DIM + lane2);
        ax += v0.x * sc0 + v1.x * sc1;
        ay += v0.y * sc0 + v1.y * sc1;
    }
    if (e < end) {
        int s0 = csr_src[e];
        float sc0 = dn_out[s0];
        float2 v0 = *(const float2*)(h + (size_t)s0 * DIM + lane2);
        ax += v0.x * sc0;
        ay += v0.y * sc0;
    }
    float sc = dn_in[node];
    float2 o = {ax * sc, ay * sc};
    *(float2*)(agg + (size_t)node * DIM + lane2) = o;
}

// ---------------- GEMM: out[i][:] = agg[i][:] @ W + bias ----------------
__global__ __launch_bounds__(256) void gemm_kernel(const float* __restrict__ A,
                                                   const float* __restrict__ W,
                                                   const float* __restrict__ bias,
                                                   float* __restrict__ out) {
    __shared__ float Ws[DIM * DIM];   // 64 KB
    __shared__ float As[DIM * 32];    // 16 KB, A^T

    int t = threadIdx.x;
    int row0 = blockIdx.x * 32;

    for (int i = t * 4; i < DIM * DIM; i += 256 * 4)
        *(float4*)&Ws[i] = *(const float4*)&W[i];

    {
        int r = t >> 3;
        int k0 = (t & 7) * 16;
        int grow = row0 + r;
        if (grow < NODES) {
            const float* ap = A + (size_t)grow * DIM + k0;
            #pragma unroll
            for (int i = 0; i < 4; ++i) {
                float4 v = *(const float4*)(ap + i * 4);
                As[(k0 + i * 4 + 0) * 32 + r] = v.x;
                As[(k0 + i * 4 + 1) * 32 + r] = v.y;
                As[(k0 + i * 4 + 2) * 32 + r] = v.z;
                As[(k0 + i * 4 + 3) * 32 + r] = v.w;
            }
        }
    }
    __syncthreads();

    int cg = t & 31;
    int rg = t >> 5;
    float acc[4][4];
    #pragma unroll
    for (int i = 0; i < 4; ++i)
        #pragma unroll
        for (int j = 0; j < 4; ++j) acc[i][j] = 0.f;

    #pragma unroll 4
    for (int k = 0; k < DIM; ++k) {
        float4 av = *(float4*)&As[k * 32 + rg * 4];
        float4 wv = *(float4*)&Ws[k * DIM + cg * 4];
        acc[0][0] += av.x * wv.x; acc[0][1] += av.x * wv.y; acc[0][2] += av.x * wv.z; acc[0][3] += av.x * wv.w;
        acc[1][0] += av.y * wv.x; acc[1][1] += av.y * wv.y; acc[1][2] += av.y * wv.z; acc[1][3] += av.y * wv.w;
        acc[2][0] += av.z * wv.x; acc[2][1] += av.z * wv.y; acc[2][2] += av.z * wv.z; acc[2][3] += av.z * wv.w;
        acc[3][0] += av.w * wv.x; acc[3][1] += av.w * wv.y; acc[3][2] += av.w * wv.z; acc[3][3] += av.w * wv.w;
    }

    float4 bv = *(const float4*)&bias[cg * 4];
    #pragma unroll
    for (int ri = 0; ri < 4; ++ri) {
        int row = row0 + rg * 4 + ri;
        if (row < NODES) {
            float4 o;
            o.x = acc[ri][0] + bv.x;
            o.y = acc[ri][1] + bv.y;
            o.z = acc[ri][2] + bv.z;
            o.w = acc[ri][3] + bv.w;
            *(float4*)&out[(size_t)row * DIM + cg * 4] = o;
        }
    }
}

// ---------------- BN column stats (sum, sumsq) ----------------
__global__ __launch_bounds__(256) void bn_stats_kernel(const float* __restrict__ h,
                                                       float* __restrict__ stats) {
    __shared__ float ssum[DIM], ssq[DIM];
    int t = threadIdx.x;
    if (t < DIM) { ssum[t] = 0.f; ssq[t] = 0.f; }
    __syncthreads();
    int c = t & 127;
    int rstep = gridDim.x * 2;
    float lsum = 0.f, lsq = 0.f;
    for (int r = blockIdx.x * 2 + (t >> 7); r < NODES; r += rstep) {
        float v = h[(size_t)r * DIM + c];
        lsum += v;
        lsq += v * v;
    }
    atomicAdd(&ssum[c], lsum);
    atomicAdd(&ssq[c], lsq);
    __syncthreads();
    if (t < DIM) {
        atomicAdd(&stats[t], ssum[t]);
        atomicAdd(&stats[DIM + t], ssq[t]);
    }
}

// ---------------- BN apply + ReLU (in place) ----------------
__global__ __launch_bounds__(256) void bn_relu_kernel(float* __restrict__ h,
                                                      const float* __restrict__ stats,
                                                      const float* __restrict__ g,
                                                      const float* __restrict__ be) {
    size_t idx = (size_t)blockIdx.x * 256 + threadIdx.x;
    if (idx >= (size_t)NODES * 32) return;
    int c = (int)(idx & 31) * 4;
    const float invN = 1.0f / NODES;
    float4 v = *(float4*)(h + idx * 4);
    float vv[4] = {v.x, v.y, v.z, v.w};
    float o[4];
    #pragma unroll
    for (int j = 0; j < 4; ++j) {
        float mu = stats[c + j] * invN;
        float var = stats[DIM + c + j] * invN - mu * mu;
        float w = g[c + j] * rsqrtf(var + EPS_BN);
        o[j] = fmaxf(w * (vv[j] - mu) + be[c + j], 0.f);
    }
    float4 r = {o[0], o[1], o[2], o[3]};
    *(float4*)(h + idx * 4) = r;
}

// ---------------- BN apply + residual + ReLU ----------------
__global__ __launch_bounds__(256) void bn_res_relu_kernel(float* __restrict__ out,
                                                          const float* __restrict__ h1,
                                                          const float* __restrict__ stats,
                                                          const float* __restrict__ g,
                                                          const float* __restrict__ be) {
    size_t idx = (size_t)blockIdx.x * 256 + threadIdx.x;
    if (idx >= (size_t)NODES * 32) return;
    int c = (int)(idx & 31) * 4;
    const float invN = 1.0f / NODES;
    float4 v = *(float4*)(out + idx * 4);
    float4 r1 = *(const float4*)(h1 + idx * 4);
    float vv[4] = {v.x, v.y, v.z, v.w};
    float rr[4] = {r1.x, r1.y, r1.z, r1.w};
    float o[4];
    #pragma unroll
    for (int j = 0; j < 4; ++j) {
        float mu = stats[c + j] * invN;
        float var = stats[DIM + c + j] * invN - mu * mu;
        float w = g[c + j] * rsqrtf(var + EPS_BN);
        o[j] = fmaxf(w * (vv[j] - mu) + be[c + j] + rr[j], 0.f);
    }
    float4 r = {o[0], o[1], o[2], o[3]};
    *(float4*)(out + idx * 4) = r;
}

extern "C" void kernel_launch(void* const* d_in, const int* in_sizes, int n_in,
                              void* d_out, int out_size, void* d_ws, size_t ws_size,
                              hipStream_t stream) {
    const float* x      = (const float*)d_in[0];
    const int*   src    = (const int*)d_in[1];
    const int*   dst    = (const int*)d_in[2];
    const float* W1     = (const float*)d_in[3];
    const float* b1     = (const float*)d_in[4];
    const float* gamma1 = (const float*)d_in[5];
    const float* beta1  = (const float*)d_in[6];
    const float* W2     = (const float*)d_in[7];
    const float* b2     = (const float*)d_in[8];
    const float* gamma2 = (const float*)d_in[9];
    const float* beta2  = (const float*)d_in[10];
    float* out = (float*)d_out;

    // workspace layout (4B units):
    //   cnt_out[N] | cnt_in[N] | cursor[N] | dn_out[N] | dn_in[N] |
    //   row_ptr[N+1] | csr_src[E] | stats[256] | agg[N*128] | h1[N*128]
    char* ws = (char*)d_ws;
    int*   cnt_out = (int*)ws;                       ws += NODES * 4;
    int*   cnt_in  = (int*)ws;                       ws += NODES * 4;
    int*   cursor  = (int*)ws;                       ws += NODES * 4;
    float* dn_out  = (float*)ws;                     ws += NODES * 4;
    float* dn_in   = (float*)ws;                     ws += NODES * 4;
    int*   row_ptr = (int*)ws;                       ws += (NODES + 1) * 4;
    int*   csr_src = (int*)ws;                       ws += EDGES * 4;
    float* stats   = (float*)ws;                     ws += 2 * DIM * 4;
    float* agg     = (float*)ws;                     ws += (size_t)NODES * DIM * 4;
    float* h1      = (float*)ws;

    const int T = 256;
    const int grid_e    = (EDGES + T - 1) / T;
    const int grid_n    = (NODES + T - 1) / T;
    const int grid_pull = (NODES + 3) / 4;
    const int grid_gemm = (NODES + 31) / 32;
    const int grid_stat = 1024;
    const int grid_elem = (NODES * 32 + T - 1) / T;

    // zero cnt_out, cnt_in, cursor (contiguous)
    hipMemsetAsync(cnt_out, 0, 3 * NODES * 4, stream);
    hipMemsetAsync(stats, 0, 2 * DIM * 4, stream);

    // graph prep
    degree_int_kernel<<<grid_e, T, 0, stream>>>(src, dst, cnt_out, cnt_in);
    scan_kernel<<<1, SCAN_T, 0, stream>>>(cnt_in, row_ptr);
    degnorm_kernel<<<grid_n, T, 0, stream>>>(cnt_out, cnt_in, dn_out, dn_in);
    csr_fill_kernel<<<grid_e, T, 0, stream>>>(src, dst, row_ptr, cursor, csr_src);

    // layer 1
    pull_kernel<<<grid_pull, T, 0, stream>>>(x, row_ptr, csr_src, dn_out, dn_in, agg);
    gemm_kernel<<<grid_gemm, T, 0, stream>>>(agg, W1, b1, h1);
    bn_stats_kernel<<<grid_stat, T, 0, stream>>>(h1, stats);
    bn_relu_kernel<<<grid_elem, T, 0, stream>>>(h1, stats, gamma1, beta1);

    hipMemsetAsync(stats, 0, 2 * DIM * 4, stream);

    // layer 2
    pull_kernel<<<grid_pull, T, 0, stream>>>(h1, row_ptr, csr_src, dn_out, dn_in, agg);
    gemm_kernel<<<grid_gemm, T, 0, stream>>>(agg, W2, b2, out);
    bn_stats_kernel<<<grid_stat, T, 0, stream>>>(out, stats);
    bn_res_relu_kernel<<<grid_elem, T, 0, stream>>>(out, h1, stats, gamma2, beta2);
}

// Round 3
// 543.141 us; speedup vs baseline: 5.4970x; 1.1713x over previous
//
#include <hip/hip_runtime.h>

#define NODES 50000
#define EDGES 800000
#define DIM 128
#define EPS_BN 1e-5f
#define SCAN_B 1024
#define SCAN_NB ((NODES + SCAN_B - 1) / SCAN_B)   // 49

// ---------------- degree histogram (int) ----------------
__global__ __launch_bounds__(256) void degree_int_kernel(const int* __restrict__ src,
                                                         const int* __restrict__ dst,
                                                         int* __restrict__ cnt_out,
                                                         int* __restrict__ cnt_in) {
    int e = blockIdx.x * 256 + threadIdx.x;
    if (e < EDGES) {
        atomicAdd(&cnt_out[src[e]], 1);
        atomicAdd(&cnt_in[dst[e]], 1);
    }
}

// ---------------- multi-block scan: phase 1 (local scan + block sums) ----------------
__global__ __launch_bounds__(SCAN_B) void scan_p1_kernel(const int* __restrict__ cnt,
                                                         int* __restrict__ row_ptr,
                                                         int* __restrict__ blk_sums) {
    __shared__ int sm[SCAN_B];
    int t = threadIdx.x;
    int idx = blockIdx.x * SCAN_B + t;
    int v = (idx < NODES) ? cnt[idx] : 0;
    sm[t] = v;
    __syncthreads();
    #pragma unroll
    for (int off = 1; off < SCAN_B; off <<= 1) {
        int u = (t >= off) ? sm[t - off] : 0;
        __syncthreads();
        sm[t] += u;
        __syncthreads();
    }
    if (idx < NODES) row_ptr[idx] = sm[t] - v;   // local exclusive
    if (t == SCAN_B - 1) blk_sums[blockIdx.x] = sm[t];
}

// ---------------- phase 2: wave-scan of block sums -> exclusive offsets ----------------
__global__ __launch_bounds__(64) void scan_p2_kernel(const int* __restrict__ blk_sums,
                                                     int* __restrict__ blk_off) {
    int t = threadIdx.x;
    int orig = (t < SCAN_NB) ? blk_sums[t] : 0;
    int v = orig;
    #pragma unroll
    for (int off = 1; off < 64; off <<= 1) {
        int u = __shfl_up(v, off);
        if (t >= off) v += u;
    }
    if (t < SCAN_NB) blk_off[t] = v - orig;
}

// ---------------- phase 3: add block offsets ----------------
__global__ __launch_bounds__(SCAN_B) void scan_p3_kernel(int* __restrict__ row_ptr,
                                                         const int* __restrict__ blk_off) {
    int t = threadIdx.x;
    int idx = blockIdx.x * SCAN_B + t;
    if (idx < NODES) row_ptr[idx] += blk_off[blockIdx.x];
    if (idx == 0) row_ptr[NODES] = EDGES;
}

// ---------------- degree -> rsqrt norm (float) ----------------
__global__ __launch_bounds__(256) void degnorm_kernel(const int* __restrict__ cnt_out,
                                                      const int* __restrict__ cnt_in,
                                                      float* __restrict__ dn_out,
                                                      float* __restrict__ dn_in) {
    int i = blockIdx.x * 256 + threadIdx.x;
    if (i < NODES) {
        dn_out[i] = rsqrtf((float)max(cnt_out[i], 1));
        dn_in[i]  = rsqrtf((float)max(cnt_in[i], 1));
    }
}

// ---------------- CSR fill (counting sort by dst) ----------------
__global__ __launch_bounds__(256) void csr_fill_kernel(const int* __restrict__ src,
                                                       const int* __restrict__ dst,
                                                       const int* __restrict__ row_ptr,
                                                       int* __restrict__ cursor,
                                                       int* __restrict__ csr_src) {
    int e = blockIdx.x * 256 + threadIdx.x;
    if (e < EDGES) {
        int d = dst[e];
        int pos = row_ptr[d] + atomicAdd(&cursor[d], 1);
        csr_src[pos] = src[e];
    }
}

// ---------------- prescale: xs[i] = x[i] * dn_out[row] ----------------
__global__ __launch_bounds__(256) void prescale_kernel(const float* __restrict__ x,
                                                       const float* __restrict__ dn_out,
                                                       float* __restrict__ xs) {
    size_t idx = (size_t)blockIdx.x * 256 + threadIdx.x;   // over N*32 float4s
    if (idx >= (size_t)NODES * 32) return;
    int row = (int)(idx >> 5);
    float sc = dn_out[row];
    float4 v = *(const float4*)(x + idx * 4);
    float4 o = {v.x * sc, v.y * sc, v.z * sc, v.w * sc};
    *(float4*)(xs + idx * 4) = o;
}

// ---------------- pull aggregation over pre-scaled features ----------------
// one wave per node; half-wave (32 lanes x float4) per edge; 2 edges/iter
__global__ __launch_bounds__(256) void pull_kernel(const float* __restrict__ hs,
                                                   const int* __restrict__ row_ptr,
                                                   const int* __restrict__ csr_src,
                                                   const float* __restrict__ dn_in,
                                                   float* __restrict__ agg) {
    int wid = threadIdx.x >> 6;
    int node = blockIdx.x * 4 + wid;
    if (node >= NODES) return;
    int lane = threadIdx.x & 63;
    int half = lane >> 5;
    int f4 = (lane & 31) * 4;
    int beg = row_ptr[node];
    int end = row_ptr[node + 1];
    float ax = 0.f, ay = 0.f, az = 0.f, aw = 0.f;
    int e = beg + half;
    // 2-deep unroll: 4 edges in flight per wave
    for (; e + 2 < end; e += 4) {
        int s0 = csr_src[e];
        int s1 = csr_src[e + 2];
        float4 v0 = *(const float4*)(hs + (size_t)s0 * DIM + f4);
        float4 v1 = *(const float4*)(hs + (size_t)s1 * DIM + f4);
        ax += v0.x + v1.x; ay += v0.y + v1.y;
        az += v0.z + v1.z; aw += v0.w + v1.w;
    }
    if (e < end) {
        int s0 = csr_src[e];
        float4 v0 = *(const float4*)(hs + (size_t)s0 * DIM + f4);
        ax += v0.x; ay += v0.y; az += v0.z; aw += v0.w;
    }
    ax += __shfl_xor(ax, 32);
    ay += __shfl_xor(ay, 32);
    az += __shfl_xor(az, 32);
    aw += __shfl_xor(aw, 32);
    if (half == 0) {
        float sc = dn_in[node];
        float4 o = {ax * sc, ay * sc, az * sc, aw * sc};
        *(float4*)(agg + (size_t)node * DIM + f4) = o;
    }
}

// ---------------- GEMM: out[i][:] = agg[i][:] @ W + bias ----------------
__global__ __launch_bounds__(256) void gemm_kernel(const float* __restrict__ A,
                                                   const float* __restrict__ W,
                                                   const float* __restrict__ bias,
                                                   float* __restrict__ out) {
    __shared__ float Ws[DIM * DIM];   // 64 KB
    __shared__ float As[DIM * 32];    // 16 KB, A^T

    int t = threadIdx.x;
    int row0 = blockIdx.x * 32;

    for (int i = t * 4; i < DIM * DIM; i += 256 * 4)
        *(float4*)&Ws[i] = *(const float4*)&W[i];

    {
        int r = t >> 3;
        int k0 = (t & 7) * 16;
        int grow = row0 + r;
        if (grow < NODES) {
            const float* ap = A + (size_t)grow * DIM + k0;
            #pragma unroll
            for (int i = 0; i < 4; ++i) {
                float4 v = *(const float4*)(ap + i * 4);
                As[(k0 + i * 4 + 0) * 32 + r] = v.x;
                As[(k0 + i * 4 + 1) * 32 + r] = v.y;
                As[(k0 + i * 4 + 2) * 32 + r] = v.z;
                As[(k0 + i * 4 + 3) * 32 + r] = v.w;
            }
        }
    }
    __syncthreads();

    int cg = t & 31;
    int rg = t >> 5;
    float acc[4][4];
    #pragma unroll
    for (int i = 0; i < 4; ++i)
        #pragma unroll
        for (int j = 0; j < 4; ++j) acc[i][j] = 0.f;

    #pragma unroll 4
    for (int k = 0; k < DIM; ++k) {
        float4 av = *(float4*)&As[k * 32 + rg * 4];
        float4 wv = *(float4*)&Ws[k * DIM + cg * 4];
        acc[0][0] += av.x * wv.x; acc[0][1] += av.x * wv.y; acc[0][2] += av.x * wv.z; acc[0][3] += av.x * wv.w;
        acc[1][0] += av.y * wv.x; acc[1][1] += av.y * wv.y; acc[1][2] += av.y * wv.z; acc[1][3] += av.y * wv.w;
        acc[2][0] += av.z * wv.x; acc[2][1] += av.z * wv.y; acc[2][2] += av.z * wv.z; acc[2][3] += av.z * wv.w;
        acc[3][0] += av.w * wv.x; acc[3][1] += av.w * wv.y; acc[3][2] += av.w * wv.z; acc[3][3] += av.w * wv.w;
    }

    float4 bv = *(const float4*)&bias[cg * 4];
    #pragma unroll
    for (int ri = 0; ri < 4; ++ri) {
        int row = row0 + rg * 4 + ri;
        if (row < NODES) {
            float4 o;
            o.x = acc[ri][0] + bv.x;
            o.y = acc[ri][1] + bv.y;
            o.z = acc[ri][2] + bv.z;
            o.w = acc[ri][3] + bv.w;
            *(float4*)&out[(size_t)row * DIM + cg * 4] = o;
        }
    }
}

// ---------------- BN column stats (sum, sumsq) ----------------
__global__ __launch_bounds__(256) void bn_stats_kernel(const float* __restrict__ h,
                                                       float* __restrict__ stats) {
    __shared__ float ssum[DIM], ssq[DIM];
    int t = threadIdx.x;
    if (t < DIM) { ssum[t] = 0.f; ssq[t] = 0.f; }
    __syncthreads();
    int c = t & 127;
    int rstep = gridDim.x * 2;
    float lsum = 0.f, lsq = 0.f;
    for (int r = blockIdx.x * 2 + (t >> 7); r < NODES; r += rstep) {
        float v = h[(size_t)r * DIM + c];
        lsum += v;
        lsq += v * v;
    }
    atomicAdd(&ssum[c], lsum);
    atomicAdd(&ssq[c], lsq);
    __syncthreads();
    if (t < DIM) {
        atomicAdd(&stats[t], ssum[t]);
        atomicAdd(&stats[DIM + t], ssq[t]);
    }
}

// ---------------- BN apply + ReLU; also emit dn_out-scaled copy for next pull ----------------
__global__ __launch_bounds__(256) void bn_relu_scale_kernel(float* __restrict__ h,
                                                            float* __restrict__ hs,
                                                            const float* __restrict__ stats,
                                                            const float* __restrict__ g,
                                                            const float* __restrict__ be,
                                                            const float* __restrict__ dn_out) {
    size_t idx = (size_t)blockIdx.x * 256 + threadIdx.x;
    if (idx >= (size_t)NODES * 32) return;
    int c = (int)(idx & 31) * 4;
    int row = (int)(idx >> 5);
    const float invN = 1.0f / NODES;
    float4 v = *(float4*)(h + idx * 4);
    float vv[4] = {v.x, v.y, v.z, v.w};
    float o[4];
    #pragma unroll
    for (int j = 0; j < 4; ++j) {
        float mu = stats[c + j] * invN;
        float var = stats[DIM + c + j] * invN - mu * mu;
        float w = g[c + j] * rsqrtf(var + EPS_BN);
        o[j] = fmaxf(w * (vv[j] - mu) + be[c + j], 0.f);
    }
    float4 r = {o[0], o[1], o[2], o[3]};
    *(float4*)(h + idx * 4) = r;
    float sc = dn_out[row];
    float4 rs = {o[0] * sc, o[1] * sc, o[2] * sc, o[3] * sc};
    *(float4*)(hs + idx * 4) = rs;
}

// ---------------- BN apply + residual + ReLU ----------------
__global__ __launch_bounds__(256) void bn_res_relu_kernel(float* __restrict__ out,
                                                          const float* __restrict__ h1,
                                                          const float* __restrict__ stats,
                                                          const float* __restrict__ g,
                                                          const float* __restrict__ be) {
    size_t idx = (size_t)blockIdx.x * 256 + threadIdx.x;
    if (idx >= (size_t)NODES * 32) return;
    int c = (int)(idx & 31) * 4;
    const float invN = 1.0f / NODES;
    float4 v = *(float4*)(out + idx * 4);
    float4 r1 = *(const float4*)(h1 + idx * 4);
    float vv[4] = {v.x, v.y, v.z, v.w};
    float rr[4] = {r1.x, r1.y, r1.z, r1.w};
    float o[4];
    #pragma unroll
    for (int j = 0; j < 4; ++j) {
        float mu = stats[c + j] * invN;
        float var = stats[DIM + c + j] * invN - mu * mu;
        float w = g[c + j] * rsqrtf(var + EPS_BN);
        o[j] = fmaxf(w * (vv[j] - mu) + be[c + j] + rr[j], 0.f);
    }
    float4 r = {o[0], o[1], o[2], o[3]};
    *(float4*)(out + idx * 4) = r;
}

extern "C" void kernel_launch(void* const* d_in, const int* in_sizes, int n_in,
                              void* d_out, int out_size, void* d_ws, size_t ws_size,
                              hipStream_t stream) {
    const float* x      = (const float*)d_in[0];
    const int*   src    = (const int*)d_in[1];
    const int*   dst    = (const int*)d_in[2];
    const float* W1     = (const float*)d_in[3];
    const float* b1     = (const float*)d_in[4];
    const float* gamma1 = (const float*)d_in[5];
    const float* beta1  = (const float*)d_in[6];
    const float* W2     = (const float*)d_in[7];
    const float* b2     = (const float*)d_in[8];
    const float* gamma2 = (const float*)d_in[9];
    const float* beta2  = (const float*)d_in[10];
    float* out = (float*)d_out;

    // workspace layout (4B units):
    //   cnt_out[N] | cnt_in[N] | cursor[N] | dn_out[N] | dn_in[N] |
    //   row_ptr[N+1] | csr_src[E] | stats[256] | scan_tmp[128] | agg[N*128] | h1[N*128]
    char* wsc = (char*)d_ws;
    int*   cnt_out  = (int*)wsc;                     wsc += NODES * 4;
    int*   cnt_in   = (int*)wsc;                     wsc += NODES * 4;
    int*   cursor   = (int*)wsc;                     wsc += NODES * 4;
    float* dn_out   = (float*)wsc;                   wsc += NODES * 4;
    float* dn_in    = (float*)wsc;                   wsc += NODES * 4;
    int*   row_ptr  = (int*)wsc;                     wsc += (NODES + 1) * 4;
    int*   csr_src  = (int*)wsc;                     wsc += EDGES * 4;
    float* stats    = (float*)wsc;                   wsc += 2 * DIM * 4;
    int*   blk_sums = (int*)wsc;                     wsc += 64 * 4;
    int*   blk_off  = (int*)wsc;                     wsc += 64 * 4;
    float* agg      = (float*)wsc;                   wsc += (size_t)NODES * DIM * 4;
    float* h1       = (float*)wsc;

    const int T = 256;
    const int grid_e    = (EDGES + T - 1) / T;
    const int grid_n    = (NODES + T - 1) / T;
    const int grid_pull = (NODES + 3) / 4;
    const int grid_gemm = (NODES + 31) / 32;
    const int grid_stat = 1024;
    const int grid_elem = (NODES * 32 + T - 1) / T;

    hipMemsetAsync(cnt_out, 0, 3 * NODES * 4, stream);
    hipMemsetAsync(stats, 0, 2 * DIM * 4, stream);

    // graph prep
    degree_int_kernel<<<grid_e, T, 0, stream>>>(src, dst, cnt_out, cnt_in);
    scan_p1_kernel<<<SCAN_NB, SCAN_B, 0, stream>>>(cnt_in, row_ptr, blk_sums);
    scan_p2_kernel<<<1, 64, 0, stream>>>(blk_sums, blk_off);
    scan_p3_kernel<<<SCAN_NB, SCAN_B, 0, stream>>>(row_ptr, blk_off);
    degnorm_kernel<<<grid_n, T, 0, stream>>>(cnt_out, cnt_in, dn_out, dn_in);
    csr_fill_kernel<<<grid_e, T, 0, stream>>>(src, dst, row_ptr, cursor, csr_src);

    // layer 1: h1 doubles as scratch for scaled x
    prescale_kernel<<<grid_elem, T, 0, stream>>>(x, dn_out, h1);
    pull_kernel<<<grid_pull, T, 0, stream>>>(h1, row_ptr, csr_src, dn_in, agg);
    gemm_kernel<<<grid_gemm, T, 0, stream>>>(agg, W1, b1, h1);
    bn_stats_kernel<<<grid_stat, T, 0, stream>>>(h1, stats);
    // h1 <- BN+ReLU (unscaled, kept for residual); out <- scaled copy (scratch)
    bn_relu_scale_kernel<<<grid_elem, T, 0, stream>>>(h1, out, stats, gamma1, beta1, dn_out);

    hipMemsetAsync(stats, 0, 2 * DIM * 4, stream);

    // layer 2: pull from scaled copy in `out`, gemm then overwrites `out`
    pull_kernel<<<grid_pull, T, 0, stream>>>(out, row_ptr, csr_src, dn_in, agg);
    gemm_kernel<<<grid_gemm, T, 0, stream>>>(agg, W2, b2, out);
    bn_stats_kernel<<<grid_stat, T, 0, stream>>>(out, stats);
    bn_res_relu_kernel<<<grid_elem, T, 0, stream>>>(out, h1, stats, gamma2, beta2);
}

// Round 4
// 497.304 us; speedup vs baseline: 6.0037x; 1.0922x over previous
//
#include <hip/hip_runtime.h>

#define NODES 50000
#define EDGES 800000
#define DIM 128
#define EPS_BN 1e-5f
#define SCAN_B 1024
#define SCAN_NB ((NODES + SCAN_B - 1) / SCAN_B)   // 49

// ---------------- degree histogram; cnt_in atomic return = CSR slot ----------------
__global__ __launch_bounds__(256) void degree_int_kernel(const int* __restrict__ src,
                                                         const int* __restrict__ dst,
                                                         int* __restrict__ cnt_out,
                                                         int* __restrict__ cnt_in,
                                                         int* __restrict__ pos) {
    int e = blockIdx.x * 256 + threadIdx.x;
    if (e < EDGES) {
        atomicAdd(&cnt_out[src[e]], 1);
        pos[e] = atomicAdd(&cnt_in[dst[e]], 1);
    }
}

// ---------------- multi-block scan: phase 1 (local scan + block sums) ----------------
__global__ __launch_bounds__(SCAN_B) void scan_p1_kernel(const int* __restrict__ cnt,
                                                         int* __restrict__ row_ptr,
                                                         int* __restrict__ blk_sums) {
    __shared__ int sm[SCAN_B];
    int t = threadIdx.x;
    int idx = blockIdx.x * SCAN_B + t;
    int v = (idx < NODES) ? cnt[idx] : 0;
    sm[t] = v;
    __syncthreads();
    #pragma unroll
    for (int off = 1; off < SCAN_B; off <<= 1) {
        int u = (t >= off) ? sm[t - off] : 0;
        __syncthreads();
        sm[t] += u;
        __syncthreads();
    }
    if (idx < NODES) row_ptr[idx] = sm[t] - v;   // local exclusive
    if (t == SCAN_B - 1) blk_sums[blockIdx.x] = sm[t];
}

// ---------------- phase 2: wave-scan of block sums -> exclusive offsets ----------------
__global__ __launch_bounds__(64) void scan_p2_kernel(const int* __restrict__ blk_sums,
                                                     int* __restrict__ blk_off) {
    int t = threadIdx.x;
    int orig = (t < SCAN_NB) ? blk_sums[t] : 0;
    int v = orig;
    #pragma unroll
    for (int off = 1; off < 64; off <<= 1) {
        int u = __shfl_up(v, off);
        if (t >= off) v += u;
    }
    if (t < SCAN_NB) blk_off[t] = v - orig;
}

// ---------------- phase 3: add block offsets + degree norms ----------------
__global__ __launch_bounds__(SCAN_B) void scan_p3_kernel(int* __restrict__ row_ptr,
                                                         const int* __restrict__ blk_off,
                                                         const int* __restrict__ cnt_out,
                                                         const int* __restrict__ cnt_in,
                                                         float* __restrict__ dn_out,
                                                         float* __restrict__ dn_in) {
    int t = threadIdx.x;
    int idx = blockIdx.x * SCAN_B + t;
    if (idx < NODES) {
        row_ptr[idx] += blk_off[blockIdx.x];
        dn_out[idx] = rsqrtf((float)max(cnt_out[idx], 1));
        dn_in[idx]  = rsqrtf((float)max(cnt_in[idx], 1));
    }
    if (idx == 0) row_ptr[NODES] = EDGES;
}

// ---------------- CSR fill (no atomics: slot precomputed) ----------------
__global__ __launch_bounds__(256) void csr_fill_kernel(const int* __restrict__ src,
                                                       const int* __restrict__ dst,
                                                       const int* __restrict__ row_ptr,
                                                       const int* __restrict__ pos,
                                                       int* __restrict__ csr_src) {
    int e = blockIdx.x * 256 + threadIdx.x;
    if (e < EDGES) {
        csr_src[row_ptr[dst[e]] + pos[e]] = src[e];
    }
}

// ---------------- prescale: xs[i] = x[i] * dn_out[row] ----------------
__global__ __launch_bounds__(256) void prescale_kernel(const float* __restrict__ x,
                                                       const float* __restrict__ dn_out,
                                                       float* __restrict__ xs) {
    size_t idx = (size_t)blockIdx.x * 256 + threadIdx.x;   // over N*32 float4s
    if (idx >= (size_t)NODES * 32) return;
    int row = (int)(idx >> 5);
    float sc = dn_out[row];
    float4 v = *(const float4*)(x + idx * 4);
    float4 o = {v.x * sc, v.y * sc, v.z * sc, v.w * sc};
    *(float4*)(xs + idx * 4) = o;
}

// ---------------- pull aggregation over pre-scaled features ----------------
// one wave per node; half-wave (32 lanes x float4) per edge; 8 edges in flight
__global__ __launch_bounds__(256) void pull_kernel(const float* __restrict__ hs,
                                                   const int* __restrict__ row_ptr,
                                                   const int* __restrict__ csr_src,
                                                   const float* __restrict__ dn_in,
                                                   float* __restrict__ agg) {
    int wid = threadIdx.x >> 6;
    int node = blockIdx.x * 4 + wid;
    if (node >= NODES) return;
    int lane = threadIdx.x & 63;
    int half = lane >> 5;
    int f4 = (lane & 31) * 4;
    int beg = row_ptr[node];
    int end = row_ptr[node + 1];
    float ax = 0.f, ay = 0.f, az = 0.f, aw = 0.f;
    int e = beg + half;
    for (; e + 6 < end; e += 8) {
        int s0 = csr_src[e];
        int s1 = csr_src[e + 2];
        int s2 = csr_src[e + 4];
        int s3 = csr_src[e + 6];
        float4 v0 = *(const float4*)(hs + (size_t)s0 * DIM + f4);
        float4 v1 = *(const float4*)(hs + (size_t)s1 * DIM + f4);
        float4 v2 = *(const float4*)(hs + (size_t)s2 * DIM + f4);
        float4 v3 = *(const float4*)(hs + (size_t)s3 * DIM + f4);
        ax += (v0.x + v1.x) + (v2.x + v3.x);
        ay += (v0.y + v1.y) + (v2.y + v3.y);
        az += (v0.z + v1.z) + (v2.z + v3.z);
        aw += (v0.w + v1.w) + (v2.w + v3.w);
    }
    for (; e < end; e += 2) {
        int s0 = csr_src[e];
        float4 v0 = *(const float4*)(hs + (size_t)s0 * DIM + f4);
        ax += v0.x; ay += v0.y; az += v0.z; aw += v0.w;
    }
    ax += __shfl_xor(ax, 32);
    ay += __shfl_xor(ay, 32);
    az += __shfl_xor(az, 32);
    aw += __shfl_xor(aw, 32);
    if (half == 0) {
        float sc = dn_in[node];
        float4 o = {ax * sc, ay * sc, az * sc, aw * sc};
        *(float4*)(agg + (size_t)node * DIM + f4) = o;
    }
}

// ---------------- GEMM: out = A @ W + bias ----------------
// 128x128 block, 256 threads, 8x8 per-thread tile, K staged in two 64-phases.
// LDS = 2 x 32 KB = 64 KB -> 2 blocks/CU.
__global__ __launch_bounds__(256) void gemm_kernel(const float* __restrict__ A,
                                                   const float* __restrict__ W,
                                                   const float* __restrict__ bias,
                                                   float* __restrict__ out) {
    __shared__ float Ws[64 * DIM];   // Ws[kk*128 + c]
    __shared__ float As[64 * DIM];   // A^T: As[kk*128 + r]

    int t = threadIdx.x;
    int row0 = blockIdx.x * 128;
    int cg = t & 15;    // col group: cols cg*8..+7
    int rg = t >> 4;    // row group: rows rg*8..+7

    float acc[8][8];
    #pragma unroll
    for (int i = 0; i < 8; ++i)
        #pragma unroll
        for (int j = 0; j < 8; ++j) acc[i][j] = 0.f;

    int r = t >> 1;            // staging row 0..127
    int kh = (t & 1) * 32;     // staging k-half within phase
    int grow = row0 + r;

    #pragma unroll
    for (int kt = 0; kt < DIM; kt += 64) {
        // stage W rows kt..kt+63 (8192 floats)
        for (int i = t * 4; i < 64 * DIM; i += 1024)
            *(float4*)&Ws[i] = *(const float4*)&W[kt * DIM + i];
        // stage A^T tile
        if (grow < NODES) {
            const float* ap = A + (size_t)grow * DIM + kt + kh;
            #pragma unroll
            for (int j = 0; j < 8; ++j) {
                float4 v = *(const float4*)(ap + j * 4);
                As[(kh + j * 4 + 0) * DIM + r] = v.x;
                As[(kh + j * 4 + 1) * DIM + r] = v.y;
                As[(kh + j * 4 + 2) * DIM + r] = v.z;
                As[(kh + j * 4 + 3) * DIM + r] = v.w;
            }
        } else {
            #pragma unroll
            for (int j = 0; j < 32; ++j)
                As[(kh + j) * DIM + r] = 0.f;
        }
        __syncthreads();

        #pragma unroll 4
        for (int kk = 0; kk < 64; ++kk) {
            float4 a0 = *(float4*)&As[kk * DIM + rg * 8];
            float4 a1 = *(float4*)&As[kk * DIM + rg * 8 + 4];
            float4 w0 = *(float4*)&Ws[kk * DIM + cg * 8];
            float4 w1 = *(float4*)&Ws[kk * DIM + cg * 8 + 4];
            float av[8] = {a0.x, a0.y, a0.z, a0.w, a1.x, a1.y, a1.z, a1.w};
            float wv[8] = {w0.x, w0.y, w0.z, w0.w, w1.x, w1.y, w1.z, w1.w};
            #pragma unroll
            for (int i = 0; i < 8; ++i)
                #pragma unroll
                for (int j = 0; j < 8; ++j)
                    acc[i][j] += av[i] * wv[j];
        }
        __syncthreads();
    }

    float4 bv0 = *(const float4*)&bias[cg * 8];
    float4 bv1 = *(const float4*)&bias[cg * 8 + 4];
    float bb[8] = {bv0.x, bv0.y, bv0.z, bv0.w, bv1.x, bv1.y, bv1.z, bv1.w};
    #pragma unroll
    for (int i = 0; i < 8; ++i) {
        int row = row0 + rg * 8 + i;
        if (row < NODES) {
            float4 o0 = {acc[i][0] + bb[0], acc[i][1] + bb[1], acc[i][2] + bb[2], acc[i][3] + bb[3]};
            float4 o1 = {acc[i][4] + bb[4], acc[i][5] + bb[5], acc[i][6] + bb[6], acc[i][7] + bb[7]};
            *(float4*)&out[(size_t)row * DIM + cg * 8] = o0;
            *(float4*)&out[(size_t)row * DIM + cg * 8 + 4] = o1;
        }
    }
}

// ---------------- BN column stats (sum, sumsq) ----------------
__global__ __launch_bounds__(256) void bn_stats_kernel(const float* __restrict__ h,
                                                       float* __restrict__ stats) {
    __shared__ float ssum[DIM], ssq[DIM];
    int t = threadIdx.x;
    if (t < DIM) { ssum[t] = 0.f; ssq[t] = 0.f; }
    __syncthreads();
    int c = t & 127;
    int rstep = gridDim.x * 2;
    float lsum = 0.f, lsq = 0.f;
    for (int r = blockIdx.x * 2 + (t >> 7); r < NODES; r += rstep) {
        float v = h[(size_t)r * DIM + c];
        lsum += v;
        lsq += v * v;
    }
    atomicAdd(&ssum[c], lsum);
    atomicAdd(&ssq[c], lsq);
    __syncthreads();
    if (t < DIM) {
        atomicAdd(&stats[t], ssum[t]);
        atomicAdd(&stats[DIM + t], ssq[t]);
    }
}

// ---------------- BN apply + ReLU; also emit dn_out-scaled copy for next pull ----------------
__global__ __launch_bounds__(256) void bn_relu_scale_kernel(float* __restrict__ h,
                                                            float* __restrict__ hs,
                                                            const float* __restrict__ stats,
                                                            const float* __restrict__ g,
                                                            const float* __restrict__ be,
                                                            const float* __restrict__ dn_out) {
    size_t idx = (size_t)blockIdx.x * 256 + threadIdx.x;
    if (idx >= (size_t)NODES * 32) return;
    int c = (int)(idx & 31) * 4;
    int row = (int)(idx >> 5);
    const float invN = 1.0f / NODES;
    float4 v = *(float4*)(h + idx * 4);
    float vv[4] = {v.x, v.y, v.z, v.w};
    float o[4];
    #pragma unroll
    for (int j = 0; j < 4; ++j) {
        float mu = stats[c + j] * invN;
        float var = stats[DIM + c + j] * invN - mu * mu;
        float w = g[c + j] * rsqrtf(var + EPS_BN);
        o[j] = fmaxf(w * (vv[j] - mu) + be[c + j], 0.f);
    }
    float4 r = {o[0], o[1], o[2], o[3]};
    *(float4*)(h + idx * 4) = r;
    float sc = dn_out[row];
    float4 rs = {o[0] * sc, o[1] * sc, o[2] * sc, o[3] * sc};
    *(float4*)(hs + idx * 4) = rs;
}

// ---------------- BN apply + residual + ReLU ----------------
__global__ __launch_bounds__(256) void bn_res_relu_kernel(float* __restrict__ out,
                                                          const float* __restrict__ h1,
                                                          const float* __restrict__ stats,
                                                          const float* __restrict__ g,
                                                          const float* __restrict__ be) {
    size_t idx = (size_t)blockIdx.x * 256 + threadIdx.x;
    if (idx >= (size_t)NODES * 32) return;
    int c = (int)(idx & 31) * 4;
    const float invN = 1.0f / NODES;
    float4 v = *(float4*)(out + idx * 4);
    float4 r1 = *(const float4*)(h1 + idx * 4);
    float vv[4] = {v.x, v.y, v.z, v.w};
    float rr[4] = {r1.x, r1.y, r1.z, r1.w};
    float o[4];
    #pragma unroll
    for (int j = 0; j < 4; ++j) {
        float mu = stats[c + j] * invN;
        float var = stats[DIM + c + j] * invN - mu * mu;
        float w = g[c + j] * rsqrtf(var + EPS_BN);
        o[j] = fmaxf(w * (vv[j] - mu) + be[c + j] + rr[j], 0.f);
    }
    float4 r = {o[0], o[1], o[2], o[3]};
    *(float4*)(out + idx * 4) = r;
}

extern "C" void kernel_launch(void* const* d_in, const int* in_sizes, int n_in,
                              void* d_out, int out_size, void* d_ws, size_t ws_size,
                              hipStream_t stream) {
    const float* x      = (const float*)d_in[0];
    const int*   src    = (const int*)d_in[1];
    const int*   dst    = (const int*)d_in[2];
    const float* W1     = (const float*)d_in[3];
    const float* b1     = (const float*)d_in[4];
    const float* gamma1 = (const float*)d_in[5];
    const float* beta1  = (const float*)d_in[6];
    const float* W2     = (const float*)d_in[7];
    const float* b2     = (const float*)d_in[8];
    const float* gamma2 = (const float*)d_in[9];
    const float* beta2  = (const float*)d_in[10];
    float* out = (float*)d_out;

    // workspace layout (4B units):
    //   cnt_out[N] | cnt_in[N] | dn_out[N] | dn_in[N] | row_ptr[N+1] |
    //   pos[E] | csr_src[E] | stats[256] | blk[128] | agg[N*128] | h1[N*128]
    char* wsc = (char*)d_ws;
    int*   cnt_out  = (int*)wsc;                     wsc += NODES * 4;
    int*   cnt_in   = (int*)wsc;                     wsc += NODES * 4;
    float* dn_out   = (float*)wsc;                   wsc += NODES * 4;
    float* dn_in    = (float*)wsc;                   wsc += NODES * 4;
    int*   row_ptr  = (int*)wsc;                     wsc += (NODES + 1) * 4;
    int*   pos      = (int*)wsc;                     wsc += EDGES * 4;
    int*   csr_src  = (int*)wsc;                     wsc += EDGES * 4;
    float* stats    = (float*)wsc;                   wsc += 2 * DIM * 4;
    int*   blk_sums = (int*)wsc;                     wsc += 64 * 4;
    int*   blk_off  = (int*)wsc;                     wsc += 64 * 4;
    float* agg      = (float*)wsc;                   wsc += (size_t)NODES * DIM * 4;
    float* h1       = (float*)wsc;

    const int T = 256;
    const int grid_e    = (EDGES + T - 1) / T;
    const int grid_pull = (NODES + 3) / 4;
    const int grid_gemm = (NODES + 127) / 128;
    const int grid_stat = 1024;
    const int grid_elem = (NODES * 32 + T - 1) / T;

    hipMemsetAsync(cnt_out, 0, 2 * NODES * 4, stream);
    hipMemsetAsync(stats, 0, 2 * DIM * 4, stream);

    // graph prep
    degree_int_kernel<<<grid_e, T, 0, stream>>>(src, dst, cnt_out, cnt_in, pos);
    scan_p1_kernel<<<SCAN_NB, SCAN_B, 0, stream>>>(cnt_in, row_ptr, blk_sums);
    scan_p2_kernel<<<1, 64, 0, stream>>>(blk_sums, blk_off);
    scan_p3_kernel<<<SCAN_NB, SCAN_B, 0, stream>>>(row_ptr, blk_off, cnt_out, cnt_in, dn_out, dn_in);
    csr_fill_kernel<<<grid_e, T, 0, stream>>>(src, dst, row_ptr, pos, csr_src);

    // layer 1: h1 doubles as scratch for scaled x
    prescale_kernel<<<grid_elem, T, 0, stream>>>(x, dn_out, h1);
    pull_kernel<<<grid_pull, T, 0, stream>>>(h1, row_ptr, csr_src, dn_in, agg);
    gemm_kernel<<<grid_gemm, T, 0, stream>>>(agg, W1, b1, h1);
    bn_stats_kernel<<<grid_stat, T, 0, stream>>>(h1, stats);
    // h1 <- BN+ReLU (unscaled, kept for residual); out <- scaled copy (scratch)
    bn_relu_scale_kernel<<<grid_elem, T, 0, stream>>>(h1, out, stats, gamma1, beta1, dn_out);

    hipMemsetAsync(stats, 0, 2 * DIM * 4, stream);

    // layer 2: pull from scaled copy in `out`, gemm then overwrites `out`
    pull_kernel<<<grid_pull, T, 0, stream>>>(out, row_ptr, csr_src, dn_in, agg);
    gemm_kernel<<<grid_gemm, T, 0, stream>>>(agg, W2, b2, out);
    bn_stats_kernel<<<grid_stat, T, 0, stream>>>(out, stats);
    bn_res_relu_kernel<<<grid_elem, T, 0, stream>>>(out, h1, stats, gamma2, beta2);
}

// Round 5
// 366.328 us; speedup vs baseline: 8.1502x; 1.3575x over previous
//
#include <hip/hip_runtime.h>
#include <hip/hip_fp16.h>

#define NODES 50000
#define EDGES 800000
#define DIM 128
#define EPS_BN 1e-5f
#define SCAN_B 1024
#define SCAN_NB ((NODES + SCAN_B - 1) / SCAN_B)   // 49
#define GEMM_NB ((NODES + 127) / 128)             // 391

// ---------------- degree histogram; cnt_in atomic return = CSR slot ----------------
__global__ __launch_bounds__(256) void degree_int_kernel(const int* __restrict__ src,
                                                         const int* __restrict__ dst,
                                                         int* __restrict__ cnt_out,
                                                         int* __restrict__ cnt_in,
                                                         int* __restrict__ pos) {
    int e = blockIdx.x * 256 + threadIdx.x;
    if (e < EDGES) {
        atomicAdd(&cnt_out[src[e]], 1);
        pos[e] = atomicAdd(&cnt_in[dst[e]], 1);
    }
}

// ---------------- multi-block scan: phase 1 ----------------
__global__ __launch_bounds__(SCAN_B) void scan_p1_kernel(const int* __restrict__ cnt,
                                                         int* __restrict__ row_ptr,
                                                         int* __restrict__ blk_sums) {
    __shared__ int sm[SCAN_B];
    int t = threadIdx.x;
    int idx = blockIdx.x * SCAN_B + t;
    int v = (idx < NODES) ? cnt[idx] : 0;
    sm[t] = v;
    __syncthreads();
    #pragma unroll
    for (int off = 1; off < SCAN_B; off <<= 1) {
        int u = (t >= off) ? sm[t - off] : 0;
        __syncthreads();
        sm[t] += u;
        __syncthreads();
    }
    if (idx < NODES) row_ptr[idx] = sm[t] - v;
    if (t == SCAN_B - 1) blk_sums[blockIdx.x] = sm[t];
}

// ---------------- phase 2: wave-scan of block sums ----------------
__global__ __launch_bounds__(64) void scan_p2_kernel(const int* __restrict__ blk_sums,
                                                     int* __restrict__ blk_off) {
    int t = threadIdx.x;
    int orig = (t < SCAN_NB) ? blk_sums[t] : 0;
    int v = orig;
    #pragma unroll
    for (int off = 1; off < 64; off <<= 1) {
        int u = __shfl_up(v, off);
        if (t >= off) v += u;
    }
    if (t < SCAN_NB) blk_off[t] = v - orig;
}

// ---------------- phase 3: add block offsets + degree norms ----------------
__global__ __launch_bounds__(SCAN_B) void scan_p3_kernel(int* __restrict__ row_ptr,
                                                         const int* __restrict__ blk_off,
                                                         const int* __restrict__ cnt_out,
                                                         const int* __restrict__ cnt_in,
                                                         float* __restrict__ dn_out,
                                                         float* __restrict__ dn_in) {
    int t = threadIdx.x;
    int idx = blockIdx.x * SCAN_B + t;
    if (idx < NODES) {
        row_ptr[idx] += blk_off[blockIdx.x];
        dn_out[idx] = rsqrtf((float)max(cnt_out[idx], 1));
        dn_in[idx]  = rsqrtf((float)max(cnt_in[idx], 1));
    }
    if (idx == 0) row_ptr[NODES] = EDGES;
}

// ---------------- CSR fill (no atomics) ----------------
__global__ __launch_bounds__(256) void csr_fill_kernel(const int* __restrict__ src,
                                                       const int* __restrict__ dst,
                                                       const int* __restrict__ row_ptr,
                                                       const int* __restrict__ pos,
                                                       int* __restrict__ csr_src) {
    int e = blockIdx.x * 256 + threadIdx.x;
    if (e < EDGES) {
        csr_src[row_ptr[dst[e]] + pos[e]] = src[e];
    }
}

// ---------------- prescale to fp16: hs[i] = (half)(x[i] * dn_out[row]) ----------------
__global__ __launch_bounds__(256) void prescale_kernel(const float* __restrict__ x,
                                                       const float* __restrict__ dn_out,
                                                       __half* __restrict__ hs) {
    size_t idx = (size_t)blockIdx.x * 256 + threadIdx.x;   // over N*32 groups of 4
    if (idx >= (size_t)NODES * 32) return;
    int row = (int)(idx >> 5);
    float sc = dn_out[row];
    float4 v = *(const float4*)(x + idx * 4);
    __half2 a = __floats2half2_rn(v.x * sc, v.y * sc);
    __half2 b = __floats2half2_rn(v.z * sc, v.w * sc);
    float2 o;
    *(__half2*)&o.x = a;
    *(__half2*)&o.y = b;
    *(float2*)((char*)hs + idx * 8) = o;
}

// ---------------- pull aggregation over pre-scaled fp16 features ----------------
// one wave per node; half-wave (32 lanes x 4 halves = 8B/lane) per edge; 8 edges in flight
__device__ __forceinline__ void acc_h4(float2 raw, float& ax, float& ay, float& az, float& aw) {
    __half2 p0 = *(__half2*)&raw.x;
    __half2 p1 = *(__half2*)&raw.y;
    float2 f0 = __half22float2(p0);
    float2 f1 = __half22float2(p1);
    ax += f0.x; ay += f0.y; az += f1.x; aw += f1.y;
}

__global__ __launch_bounds__(256) void pull_kernel(const __half* __restrict__ hs,
                                                   const int* __restrict__ row_ptr,
                                                   const int* __restrict__ csr_src,
                                                   const float* __restrict__ dn_in,
                                                   float* __restrict__ agg) {
    int wid = threadIdx.x >> 6;
    int node = blockIdx.x * 4 + wid;
    if (node >= NODES) return;
    int lane = threadIdx.x & 63;
    int half = lane >> 5;
    int f4 = (lane & 31) * 4;
    const char* base = (const char*)hs;
    int beg = row_ptr[node];
    int end = row_ptr[node + 1];
    float ax = 0.f, ay = 0.f, az = 0.f, aw = 0.f;
    int e = beg + half;
    for (; e + 6 < end; e += 8) {
        int s0 = csr_src[e];
        int s1 = csr_src[e + 2];
        int s2 = csr_src[e + 4];
        int s3 = csr_src[e + 6];
        float2 r0 = *(const float2*)(base + ((size_t)s0 * DIM + f4) * 2);
        float2 r1 = *(const float2*)(base + ((size_t)s1 * DIM + f4) * 2);
        float2 r2 = *(const float2*)(base + ((size_t)s2 * DIM + f4) * 2);
        float2 r3 = *(const float2*)(base + ((size_t)s3 * DIM + f4) * 2);
        acc_h4(r0, ax, ay, az, aw);
        acc_h4(r1, ax, ay, az, aw);
        acc_h4(r2, ax, ay, az, aw);
        acc_h4(r3, ax, ay, az, aw);
    }
    for (; e < end; e += 2) {
        int s0 = csr_src[e];
        float2 r0 = *(const float2*)(base + ((size_t)s0 * DIM + f4) * 2);
        acc_h4(r0, ax, ay, az, aw);
    }
    ax += __shfl_xor(ax, 32);
    ay += __shfl_xor(ay, 32);
    az += __shfl_xor(az, 32);
    aw += __shfl_xor(aw, 32);
    if (half == 0) {
        float sc = dn_in[node];
        float4 o = {ax * sc, ay * sc, az * sc, aw * sc};
        *(float4*)(agg + (size_t)node * DIM + f4) = o;
    }
}

// ---------------- GEMM + fused BN partial stats ----------------
// 128x128 block, 256 threads, 8x8 per-thread tile, K in two 64-phases.
// Epilogue: per-block column sum/sumsq -> partial[block][256] (non-atomic).
__global__ __launch_bounds__(256) void gemm_stats_kernel(const float* __restrict__ A,
                                                         const float* __restrict__ W,
                                                         const float* __restrict__ bias,
                                                         float* __restrict__ out,
                                                         float* __restrict__ partial) {
    __shared__ float Ws[64 * DIM];
    __shared__ float As[64 * DIM];
    __shared__ float ps[2 * 16 * DIM];   // psum[16][128] | psq[16][128]

    int t = threadIdx.x;
    int row0 = blockIdx.x * 128;
    int cg = t & 15;
    int rg = t >> 4;

    float acc[8][8];
    #pragma unroll
    for (int i = 0; i < 8; ++i)
        #pragma unroll
        for (int j = 0; j < 8; ++j) acc[i][j] = 0.f;

    int r = t >> 1;
    int kh = (t & 1) * 32;
    int grow = row0 + r;

    #pragma unroll
    for (int kt = 0; kt < DIM; kt += 64) {
        for (int i = t * 4; i < 64 * DIM; i += 1024)
            *(float4*)&Ws[i] = *(const float4*)&W[kt * DIM + i];
        if (grow < NODES) {
            const float* ap = A + (size_t)grow * DIM + kt + kh;
            #pragma unroll
            for (int j = 0; j < 8; ++j) {
                float4 v = *(const float4*)(ap + j * 4);
                As[(kh + j * 4 + 0) * DIM + r] = v.x;
                As[(kh + j * 4 + 1) * DIM + r] = v.y;
                As[(kh + j * 4 + 2) * DIM + r] = v.z;
                As[(kh + j * 4 + 3) * DIM + r] = v.w;
            }
        } else {
            #pragma unroll
            for (int j = 0; j < 32; ++j)
                As[(kh + j) * DIM + r] = 0.f;
        }
        __syncthreads();

        #pragma unroll 4
        for (int kk = 0; kk < 64; ++kk) {
            float4 a0 = *(float4*)&As[kk * DIM + rg * 8];
            float4 a1 = *(float4*)&As[kk * DIM + rg * 8 + 4];
            float4 w0 = *(float4*)&Ws[kk * DIM + cg * 8];
            float4 w1 = *(float4*)&Ws[kk * DIM + cg * 8 + 4];
            float av[8] = {a0.x, a0.y, a0.z, a0.w, a1.x, a1.y, a1.z, a1.w};
            float wv[8] = {w0.x, w0.y, w0.z, w0.w, w1.x, w1.y, w1.z, w1.w};
            #pragma unroll
            for (int i = 0; i < 8; ++i)
                #pragma unroll
                for (int j = 0; j < 8; ++j)
                    acc[i][j] += av[i] * wv[j];
        }
        __syncthreads();
    }

    float4 bv0 = *(const float4*)&bias[cg * 8];
    float4 bv1 = *(const float4*)&bias[cg * 8 + 4];
    float bb[8] = {bv0.x, bv0.y, bv0.z, bv0.w, bv1.x, bv1.y, bv1.z, bv1.w};
    float csum[8], csq[8];
    #pragma unroll
    for (int j = 0; j < 8; ++j) { csum[j] = 0.f; csq[j] = 0.f; }

    #pragma unroll
    for (int i = 0; i < 8; ++i) {
        int row = row0 + rg * 8 + i;
        if (row < NODES) {
            float o[8];
            #pragma unroll
            for (int j = 0; j < 8; ++j) {
                o[j] = acc[i][j] + bb[j];
                csum[j] += o[j];
                csq[j] += o[j] * o[j];
            }
            float4 o0 = {o[0], o[1], o[2], o[3]};
            float4 o1 = {o[4], o[5], o[6], o[7]};
            *(float4*)&out[(size_t)row * DIM + cg * 8] = o0;
            *(float4*)&out[(size_t)row * DIM + cg * 8 + 4] = o1;
        }
    }

    // per-block column reduction: 16 row-groups -> 1
    #pragma unroll
    for (int j = 0; j < 8; ++j) {
        ps[rg * DIM + cg * 8 + j] = csum[j];
        ps[16 * DIM + rg * DIM + cg * 8 + j] = csq[j];
    }
    __syncthreads();
    if (t < DIM) {
        float s = 0.f;
        #pragma unroll
        for (int g = 0; g < 16; ++g) s += ps[g * DIM + t];
        partial[(size_t)blockIdx.x * 256 + t] = s;
    } else {
        int c = t - DIM;
        float s = 0.f;
        #pragma unroll
        for (int g = 0; g < 16; ++g) s += ps[16 * DIM + g * DIM + c];
        partial[(size_t)blockIdx.x * 256 + DIM + c] = s;
    }
}

// ---------------- reduce per-block partials -> stats[256] ----------------
__global__ __launch_bounds__(256) void stats_reduce_kernel(const float* __restrict__ partial,
                                                           float* __restrict__ stats) {
    int t = threadIdx.x;
    float s = 0.f;
    for (int b = 0; b < GEMM_NB; ++b) s += partial[(size_t)b * 256 + t];
    stats[t] = s;
}

// ---------------- BN apply + ReLU; emit fp16 dn_out-scaled copy for next pull ----------------
__global__ __launch_bounds__(256) void bn_relu_scale_kernel(float* __restrict__ h,
                                                            __half* __restrict__ hs,
                                                            const float* __restrict__ stats,
                                                            const float* __restrict__ g,
                                                            const float* __restrict__ be,
                                                            const float* __restrict__ dn_out) {
    size_t idx = (size_t)blockIdx.x * 256 + threadIdx.x;
    if (idx >= (size_t)NODES * 32) return;
    int c = (int)(idx & 31) * 4;
    int row = (int)(idx >> 5);
    const float invN = 1.0f / NODES;
    float4 v = *(float4*)(h + idx * 4);
    float vv[4] = {v.x, v.y, v.z, v.w};
    float o[4];
    #pragma unroll
    for (int j = 0; j < 4; ++j) {
        float mu = stats[c + j] * invN;
        float var = stats[DIM + c + j] * invN - mu * mu;
        float w = g[c + j] * rsqrtf(var + EPS_BN);
        o[j] = fmaxf(w * (vv[j] - mu) + be[c + j], 0.f);
    }
    float4 r = {o[0], o[1], o[2], o[3]};
    *(float4*)(h + idx * 4) = r;
    float sc = dn_out[row];
    __half2 a = __floats2half2_rn(o[0] * sc, o[1] * sc);
    __half2 b = __floats2half2_rn(o[2] * sc, o[3] * sc);
    float2 rs;
    *(__half2*)&rs.x = a;
    *(__half2*)&rs.y = b;
    *(float2*)((char*)hs + idx * 8) = rs;
}

// ---------------- BN apply + residual + ReLU ----------------
__global__ __launch_bounds__(256) void bn_res_relu_kernel(float* __restrict__ out,
                                                          const float* __restrict__ h1,
                                                          const float* __restrict__ stats,
                                                          const float* __restrict__ g,
                                                          const float* __restrict__ be) {
    size_t idx = (size_t)blockIdx.x * 256 + threadIdx.x;
    if (idx >= (size_t)NODES * 32) return;
    int c = (int)(idx & 31) * 4;
    const float invN = 1.0f / NODES;
    float4 v = *(float4*)(out + idx * 4);
    float4 r1 = *(const float4*)(h1 + idx * 4);
    float vv[4] = {v.x, v.y, v.z, v.w};
    float rr[4] = {r1.x, r1.y, r1.z, r1.w};
    float o[4];
    #pragma unroll
    for (int j = 0; j < 4; ++j) {
        float mu = stats[c + j] * invN;
        float var = stats[DIM + c + j] * invN - mu * mu;
        float w = g[c + j] * rsqrtf(var + EPS_BN);
        o[j] = fmaxf(w * (vv[j] - mu) + be[c + j] + rr[j], 0.f);
    }
    float4 r = {o[0], o[1], o[2], o[3]};
    *(float4*)(out + idx * 4) = r;
}

extern "C" void kernel_launch(void* const* d_in, const int* in_sizes, int n_in,
                              void* d_out, int out_size, void* d_ws, size_t ws_size,
                              hipStream_t stream) {
    const float* x      = (const float*)d_in[0];
    const int*   src    = (const int*)d_in[1];
    const int*   dst    = (const int*)d_in[2];
    const float* W1     = (const float*)d_in[3];
    const float* b1     = (const float*)d_in[4];
    const float* gamma1 = (const float*)d_in[5];
    const float* beta1  = (const float*)d_in[6];
    const float* W2     = (const float*)d_in[7];
    const float* b2     = (const float*)d_in[8];
    const float* gamma2 = (const float*)d_in[9];
    const float* beta2  = (const float*)d_in[10];
    float* out = (float*)d_out;
    // fp16 scratch lives in d_out's first 12.8 MB (out = 25.6 MB, overwritten
    // by layer-2 gemm AFTER the last pull has consumed hs).
    __half* hs = (__half*)d_out;

    // workspace (4B units): cnt_out[N] | cnt_in[N] | dn_out[N] | dn_in[N] |
    //   row_ptr[N+1] | pos[E] | csr_src[E] | stats[256] | blk[128] |
    //   partial[391*256] | agg[N*128] | h1[N*128]
    char* wsc = (char*)d_ws;
    int*   cnt_out  = (int*)wsc;                     wsc += NODES * 4;
    int*   cnt_in   = (int*)wsc;                     wsc += NODES * 4;
    float* dn_out   = (float*)wsc;                   wsc += NODES * 4;
    float* dn_in    = (float*)wsc;                   wsc += NODES * 4;
    int*   row_ptr  = (int*)wsc;                     wsc += (NODES + 1) * 4;
    int*   pos      = (int*)wsc;                     wsc += EDGES * 4;
    int*   csr_src  = (int*)wsc;                     wsc += EDGES * 4;
    float* stats    = (float*)wsc;                   wsc += 2 * DIM * 4;
    int*   blk_sums = (int*)wsc;                     wsc += 64 * 4;
    int*   blk_off  = (int*)wsc;                     wsc += 64 * 4;
    float* partial  = (float*)wsc;                   wsc += (size_t)GEMM_NB * 256 * 4;
    float* agg      = (float*)wsc;                   wsc += (size_t)NODES * DIM * 4;
    float* h1       = (float*)wsc;

    const int T = 256;
    const int grid_e    = (EDGES + T - 1) / T;
    const int grid_pull = (NODES + 3) / 4;
    const int grid_elem = (NODES * 32 + T - 1) / T;

    hipMemsetAsync(cnt_out, 0, 2 * NODES * 4, stream);

    // graph prep
    degree_int_kernel<<<grid_e, T, 0, stream>>>(src, dst, cnt_out, cnt_in, pos);
    scan_p1_kernel<<<SCAN_NB, SCAN_B, 0, stream>>>(cnt_in, row_ptr, blk_sums);
    scan_p2_kernel<<<1, 64, 0, stream>>>(blk_sums, blk_off);
    scan_p3_kernel<<<SCAN_NB, SCAN_B, 0, stream>>>(row_ptr, blk_off, cnt_out, cnt_in, dn_out, dn_in);
    csr_fill_kernel<<<grid_e, T, 0, stream>>>(src, dst, row_ptr, pos, csr_src);

    // layer 1
    prescale_kernel<<<grid_elem, T, 0, stream>>>(x, dn_out, hs);
    pull_kernel<<<grid_pull, T, 0, stream>>>(hs, row_ptr, csr_src, dn_in, agg);
    gemm_stats_kernel<<<GEMM_NB, T, 0, stream>>>(agg, W1, b1, h1, partial);
    stats_reduce_kernel<<<1, T, 0, stream>>>(partial, stats);
    // h1 <- BN+ReLU (fp32, kept for residual); hs <- fp16 scaled copy
    bn_relu_scale_kernel<<<grid_elem, T, 0, stream>>>(h1, hs, stats, gamma1, beta1, dn_out);

    // layer 2: pull consumes hs (in d_out) BEFORE gemm overwrites d_out
    pull_kernel<<<grid_pull, T, 0, stream>>>(hs, row_ptr, csr_src, dn_in, agg);
    gemm_stats_kernel<<<GEMM_NB, T, 0, stream>>>(agg, W2, b2, out, partial);
    stats_reduce_kernel<<<1, T, 0, stream>>>(partial, stats);
    bn_res_relu_kernel<<<grid_elem, T, 0, stream>>>(out, h1, stats, gamma2, beta2);
}